// Round 7
// baseline (113.779 us; speedup 1.0000x reference)
//
#include <hip/hip_runtime.h>
#include <hip/hip_bf16.h>

#define NT   512          // threads per block
#define FD   128          // feature dim
#define NPGc 32           // nodes per graph (level 0)
#define Bc   128          // graphs
#define K1c  16           // nodes per graph after pool 1
#define K2c  8            // nodes per graph after pool 2
#define EPSc 1e-5f
#define SLOPEc 0.2f

struct Params {
  const float *x;
  const float *p1_rel_w, *p1_rel_b, *p1_root_w, *p1_lin_w, *p1_lin_b,
              *p1_att_w, *p1_att_b, *p1_le1_w, *p1_le1_b, *p1_le2_w,
              *p1_le3_w, *p1_le3_b;
  const float *p2_rel_w, *p2_rel_b, *p2_root_w, *p2_lin_w, *p2_lin_b,
              *p2_att_w, *p2_att_b, *p2_le1_w, *p2_le1_b, *p2_le2_w,
              *p2_le3_w, *p2_le3_b;
  const float *c1w, *c2w, *ggw, *ggb, *gnw, *gnb;
  const int *ei;
  float *out;            // FLOAT32 output (the round-6 discovery)
  int etot;
};

// Out[ROWS][128] = A1[ROWS][128] @ W1[128][128] (+ A2s@W2) (+ bias)
template<int ROWS, bool FUSE2>
__device__ __forceinline__ void mm128(const float* __restrict__ A1,
                                      const float* __restrict__ W1,
                                      const float* __restrict__ A2s,
                                      const float* __restrict__ W2,
                                      const float* __restrict__ bias,
                                      float* __restrict__ Out, int tid) {
  constexpr int RPG = ROWS / 4;
  const int fo = tid & 127;
  const int rbase = (tid >> 7) * RPG;
  float acc[RPG];
#pragma unroll
  for (int r = 0; r < RPG; ++r) acc[r] = bias ? bias[fo] : 0.f;
  for (int k = 0; k < FD; ++k) {
    float w1 = W1[k * FD + fo];
    float w2 = 0.f;
    if constexpr (FUSE2) w2 = W2[k * FD + fo];
#pragma unroll
    for (int r = 0; r < RPG; ++r) {
      acc[r] += A1[(rbase + r) * FD + k] * w1;
      if constexpr (FUSE2) acc[r] += A2s[(rbase + r) * FD + k] * w2;
    }
  }
#pragma unroll
  for (int r = 0; r < RPG; ++r) Out[(rbase + r) * FD + fo] = acc[r];
}

__global__ __launch_bounds__(NT)
void mol_kernel(Params p) {
  const int g = blockIdx.x;
  const int tid = threadIdx.x;

  __shared__ float sx [NPGc * FD];
  __shared__ float bufA[NPGc * FD];
  __shared__ float xp [NPGc * FD];
  __shared__ float xq [NPGc * FD];
  __shared__ float xcb[NPGc * FD];
  __shared__ float Am [NPGc * NPGc];
  __shared__ float Sm [NPGc * NPGc];
  __shared__ float Mm [NPGc * K1c];
  __shared__ float Hh [K1c * FD];
  __shared__ float X1 [K1c * FD];
  __shared__ float A2m[K1c * K1c];
  __shared__ float fitS[NPGc];
  __shared__ float degI[NPGc];
  __shared__ float dqS[NPGc], dpS[NPGc];
  __shared__ float sA[NPGc], sB[NPGc], sC[NPGc];
  __shared__ int   selS[NPGc];
  __shared__ float gateS[K2c];

  float* Tb  = bufA;
  float* T2b = bufA + K1c * FD;
  float* ag2 = xp;
  float* xp2 = xp + K1c * FD;
  float* xq2 = xq;
  float* xc2 = xq + K1c * FD;
  float* S2m = xcb;
  float* A3m = xcb + 256;
  float* h2b = xcb + 512;
  float* x2b = xcb + 1536;

  for (int i = tid; i < NPGc * FD; i += NT) sx[i] = p.x[g * NPGc * FD + i];
  for (int i = tid; i < NPGc * NPGc; i += NT) Am[i] = 0.f;
  __syncthreads();

  // ---- r1: mean @ +384, max @ +512 (float32 out) ----
  if (tid < FD) {
    float s = 0.f, m = -1e30f;
    for (int i = 0; i < NPGc; ++i) { float v = sx[i * FD + tid]; s += v; m = fmaxf(m, v); }
    p.out[g * 640 + 384 + tid] = s * (1.f / NPGc);
    p.out[g * 640 + 512 + tid] = m;
  }

  // ---- dense multiplicity matrix ----
  for (int e = tid; e < p.etot; e += NT) {
    int s = p.ei[e];
    if ((s >> 5) == g) {
      int d = p.ei[p.etot + e] & 31;
      atomicAdd(&Am[(s & 31) * NPGc + d], 1.f);
    }
  }
  if (tid < NPGc) atomicAdd(&Am[tid * NPGc + tid], 1.f);
  __syncthreads();

  if (tid < NPGc) {
    float s = 0.f;
    for (int i = 0; i < NPGc; ++i) s += Am[i * NPGc + tid];
    degI[tid] = s;
  }
  for (int idx = tid; idx < NPGc * FD; idx += NT) {
    int d = idx >> 7, f = idx & 127;
    float s = 0.f;
    for (int i = 0; i < NPGc; ++i) s += Am[i * NPGc + d] * sx[i * FD + f];
    bufA[idx] = s;
  }
  __syncthreads();

  mm128<NPGc, true>(bufA, p.p1_rel_w, sx, p.p1_root_w, p.p1_rel_b, xp, tid);
  __syncthreads();

  for (int idx = tid; idx < NPGc * FD; idx += NT) {
    int d = idx >> 7, f = idx & 127;
    float m = -1e30f;
    for (int i = 0; i < NPGc; ++i)
      if (Am[i * NPGc + d] > 0.f) m = fmaxf(m, xp[i * FD + f]);
    xcb[idx] = m;
  }
  __syncthreads();
  mm128<NPGc, false>(xcb, p.p1_lin_w, nullptr, nullptr, p.p1_lin_b, xq, tid);
  __syncthreads();

  if (tid < 2 * NPGc) {
    int i = tid & 31;
    const float* v = (tid < NPGc) ? (xq + i * FD) : (xp + i * FD);
    const float* w = (tid < NPGc) ? p.p1_att_w : (p.p1_att_w + FD);
    float s = 0.f;
    for (int f = 0; f < FD; ++f) s += v[f] * w[f];
    if (tid < NPGc) dqS[i] = s; else dpS[i] = s;
  }
  __syncthreads();

  if (tid < NPGc) {
    int d = tid;
    float ab = p.p1_att_b[0];
    float m = -1e30f;
    for (int s2 = 0; s2 < NPGc; ++s2)
      if (Am[s2 * NPGc + d] > 0.f) {
        float l = dqS[d] + dpS[s2] + ab;
        l = (l > 0.f) ? l : SLOPEc * l;
        m = fmaxf(m, l);
      }
    float den = 0.f;
    for (int s2 = 0; s2 < NPGc; ++s2) {
      float v = 0.f, mult = Am[s2 * NPGc + d];
      if (mult > 0.f) {
        float l = dqS[d] + dpS[s2] + ab;
        l = (l > 0.f) ? l : SLOPEc * l;
        v = mult * expf(l - m);
        den += v;
      }
      Sm[s2 * NPGc + d] = v;
    }
    float inv = 1.f / den;
    for (int s2 = 0; s2 < NPGc; ++s2) Sm[s2 * NPGc + d] *= inv;
  }
  __syncthreads();

  for (int idx = tid; idx < NPGc * FD; idx += NT) {
    int d = idx >> 7, f = idx & 127;
    float s = 0.f;
    for (int i = 0; i < NPGc; ++i) s += Sm[i * NPGc + d] * sx[i * FD + f];
    xcb[idx] = s;
  }
  __syncthreads();

  if (tid < NPGc) {
    const float* v = xcb + tid * FD;
    float a = 0.f, b = 0.f, c = 0.f;
    for (int f = 0; f < FD; ++f) { float xv = v[f]; a += xv * p.p1_le1_w[f]; b += xv * p.p1_le2_w[f]; c += xv * p.p1_le3_w[f]; }
    sA[tid] = a + p.p1_le1_b[0]; sB[tid] = b; sC[tid] = c;
  }
  __syncthreads();
  if (tid < NPGc) {
    int d = tid;
    float s = 0.f;
    for (int i = 0; i < NPGc; ++i) s += Am[i * NPGc + d] * sA[i];
    float fv = s - degI[d] * sB[d] + sC[d] + p.p1_le3_b[0];
    fitS[d] = 1.f / (1.f + expf(-fv));
  }
  __syncthreads();

  if (tid < NPGc) {
    float fi = fitS[tid]; int r = 0;
    for (int j = 0; j < NPGc; ++j) { float fj = fitS[j]; r += (fj > fi) || (fj == fi && j < tid); }
    if (r < K1c) selS[r] = tid;
  }
  __syncthreads();

  for (int idx = tid; idx < K1c * FD; idx += NT) {
    int r = idx >> 7, f = idx & 127;
    int n = selS[r] & 31;
    Hh[idx] = xcb[n * FD + f] * fitS[n];
    X1[idx] = sx[n * FD + f];
  }
  __syncthreads();

  for (int idx = tid; idx < NPGc * K1c; idx += NT) {
    int i = idx >> 4, c = idx & 15;
    float s = 0.f; int sc = selS[c] & 31;
    for (int j = 0; j < NPGc; ++j) s += Am[i * NPGc + j] * Sm[j * NPGc + sc];
    Mm[idx] = s;
  }
  __syncthreads();
  for (int idx = tid; idx < K1c * K1c; idx += NT) {
    int r = idx >> 4, c = idx & 15;
    float s = 0.f; int sr = selS[r] & 31;
    for (int i = 0; i < NPGc; ++i) s += Sm[i * NPGc + sr] * Mm[i * K1c + c];
    A2m[idx] = (r == c || s != 0.f) ? 1.f : 0.f;
  }
  __syncthreads();

  // ---- GCN2 conv1 ----
  if (tid < K1c) {
    float s = 0.f;
    for (int i = 0; i < K1c; ++i) s += A2m[i * K1c + tid];
    dqS[tid] = 1.f / sqrtf(s);
  }
  __syncthreads();
  for (int idx = tid; idx < K1c * FD; idx += NT) {
    int j = idx >> 7, f = idx & 127;
    float s = 0.f;
    for (int i = 0; i < K1c; ++i) s += dqS[i] * A2m[i * K1c + j] * Hh[i * FD + f];
    Tb[idx] = 0.8f * dqS[j] * s + 0.2f * X1[idx];
  }
  __syncthreads();
  mm128<K1c, false>(Tb, p.c1w, nullptr, nullptr, nullptr, Hh, tid);
  __syncthreads();
  if (tid < FD) {                  // inst-norm + relu + r2 (mean@+128, max@+256)
    float mean = 0.f;
    for (int i = 0; i < K1c; ++i) mean += Hh[i * FD + tid];
    mean *= (1.f / K1c);
    float var = 0.f;
    for (int i = 0; i < K1c; ++i) { float d = Hh[i * FD + tid] - mean; var += d * d; }
    var *= (1.f / K1c);
    float rstd = 1.f / sqrtf(var + EPSc);
    float s = 0.f, mx = -1e30f;
    for (int i = 0; i < K1c; ++i) {
      float v = (Hh[i * FD + tid] - mean) * rstd;
      v = v > 0.f ? v : 0.f;
      Hh[i * FD + tid] = v;
      s += v; mx = fmaxf(mx, v);
    }
    p.out[g * 640 + 128 + tid] = s * (1.f / K1c);
    p.out[g * 640 + 256 + tid] = mx;
  }
  __syncthreads();

  // ---- level 2 ----
  for (int idx = tid; idx < K1c * FD; idx += NT) {
    int j = idx >> 7, f = idx & 127;
    float s = 0.f;
    for (int i = 0; i < K1c; ++i) s += A2m[i * K1c + j] * Hh[i * FD + f];
    ag2[idx] = s;
  }
  __syncthreads();
  mm128<K1c, true>(ag2, p.p2_rel_w, Hh, p.p2_root_w, p.p2_rel_b, xp2, tid);
  __syncthreads();
  for (int idx = tid; idx < K1c * FD; idx += NT) {
    int j = idx >> 7, f = idx & 127;
    float m = -1e30f;
    for (int i = 0; i < K1c; ++i)
      if (A2m[i * K1c + j] > 0.f) m = fmaxf(m, xp2[i * FD + f]);
    Tb[idx] = m;
  }
  __syncthreads();
  mm128<K1c, false>(Tb, p.p2_lin_w, nullptr, nullptr, p.p2_lin_b, xq2, tid);
  __syncthreads();
  if (tid < 2 * K1c) {
    int i = tid & 15;
    const float* v = (tid < K1c) ? (xq2 + i * FD) : (xp2 + i * FD);
    const float* w = (tid < K1c) ? p.p2_att_w : (p.p2_att_w + FD);
    float s = 0.f;
    for (int f = 0; f < FD; ++f) s += v[f] * w[f];
    if (tid < K1c) dqS[i] = s; else dpS[i] = s;
  }
  __syncthreads();
  if (tid < K1c) {
    int j = tid;
    float ab = p.p2_att_b[0];
    float m = -1e30f;
    for (int i = 0; i < K1c; ++i)
      if (A2m[i * K1c + j] > 0.f) {
        float l = dpS[i] + dqS[j] + ab;
        l = l > 0.f ? l : SLOPEc * l;
        m = fmaxf(m, l);
      }
    float ssum = 0.f;
    for (int i = 0; i < K1c; ++i) {
      float v = 0.f;
      if (A2m[i * K1c + j] > 0.f) {
        float l = dpS[i] + dqS[j] + ab;
        l = l > 0.f ? l : SLOPEc * l;
        v = expf(l - m);
        ssum += v;
      }
      S2m[i * K1c + j] = v;
    }
    float inv = 1.f / ssum;
    for (int i = 0; i < K1c; ++i) S2m[i * K1c + j] *= inv;
  }
  __syncthreads();
  for (int idx = tid; idx < K1c * FD; idx += NT) {
    int j = idx >> 7, f = idx & 127;
    float s = 0.f;
    for (int i = 0; i < K1c; ++i) s += S2m[i * K1c + j] * Hh[i * FD + f];
    xc2[idx] = s;
  }
  __syncthreads();
  if (tid < K1c) {
    const float* v = xc2 + tid * FD;
    float a = 0.f, b = 0.f, c = 0.f;
    for (int f = 0; f < FD; ++f) { float xv = v[f]; a += xv * p.p2_le1_w[f]; b += xv * p.p2_le2_w[f]; c += xv * p.p2_le3_w[f]; }
    sA[tid] = a + p.p2_le1_b[0]; sB[tid] = b; sC[tid] = c;
  }
  __syncthreads();
  if (tid < K1c) {
    int j = tid;
    float s = 0.f, deg = 0.f;
    for (int i = 0; i < K1c; ++i) { float av = A2m[i * K1c + j]; s += av * sA[i]; deg += av; }
    float fv = s - deg * sB[j] + sC[j] + p.p2_le3_b[0];
    fitS[j] = 1.f / (1.f + expf(-fv));
  }
  __syncthreads();
  if (tid < K1c) {
    float fi = fitS[tid]; int r = 0;
    for (int j = 0; j < K1c; ++j) { float fj = fitS[j]; r += (fj > fi) || (fj == fi && j < tid); }
    if (r < K2c) selS[r] = tid;
  }
  __syncthreads();
  for (int idx = tid; idx < K2c * FD; idx += NT) {
    int r = idx >> 7, f = idx & 127;
    int n = selS[r] & 15;
    h2b[idx] = xc2[n * FD + f] * fitS[n];
    x2b[idx] = X1[n * FD + f];
  }
  for (int idx = tid; idx < K1c * K2c; idx += NT) {
    int i = idx >> 3, c = idx & 7;
    float s = 0.f; int sc = selS[c] & 15;
    for (int j = 0; j < K1c; ++j) s += A2m[i * K1c + j] * S2m[j * K1c + sc];
    Mm[idx] = s;
  }
  __syncthreads();
  for (int idx = tid; idx < K2c * K2c; idx += NT) {
    int r = idx >> 3, c = idx & 7;
    float s = 0.f; int sr = selS[r] & 15;
    for (int i = 0; i < K1c; ++i) s += S2m[i * K1c + sr] * Mm[i * K2c + c];
    A3m[idx] = (r == c || s != 0.f) ? 1.f : 0.f;
  }
  __syncthreads();

  // ---- GCN2 conv2 ----
  if (tid < K2c) {
    float s = 0.f;
    for (int i = 0; i < K2c; ++i) s += A3m[i * K2c + tid];
    dqS[tid] = 1.f / sqrtf(s);
  }
  __syncthreads();
  for (int idx = tid; idx < K2c * FD; idx += NT) {
    int j = idx >> 7, f = idx & 127;
    float s = 0.f;
    for (int i = 0; i < K2c; ++i) s += dqS[i] * A3m[i * K2c + j] * h2b[i * FD + f];
    T2b[idx] = 0.8f * dqS[j] * s + 0.2f * x2b[idx];
  }
  __syncthreads();
  mm128<K2c, false>(T2b, p.c2w, nullptr, nullptr, nullptr, h2b, tid);
  __syncthreads();
  if (tid < FD) {
    float mean = 0.f;
    for (int i = 0; i < K2c; ++i) mean += h2b[i * FD + tid];
    mean *= (1.f / K2c);
    float var = 0.f;
    for (int i = 0; i < K2c; ++i) { float d = h2b[i * FD + tid] - mean; var += d * d; }
    var *= (1.f / K2c);
    float rstd = 1.f / sqrtf(var + EPSc);
    for (int i = 0; i < K2c; ++i) {
      float v = (h2b[i * FD + tid] - mean) * rstd;
      h2b[i * FD + tid] = v > 0.f ? v : 0.f;
    }
  }
  __syncthreads();

  if (tid < K2c) {
    const float* v = h2b + tid * FD;
    float s = 0.f;
    for (int f = 0; f < FD; ++f) s += v[f] * p.ggw[f];
    gateS[tid] = s + p.ggb[0];
  }
  __syncthreads();
  if (tid < K2c) {
    float m = -1e30f;
    for (int i = 0; i < K2c; ++i) m = fmaxf(m, gateS[i]);
    float e = expf(gateS[tid] - m);
    float ssum = 0.f;
    for (int i = 0; i < K2c; ++i) ssum += expf(gateS[i] - m);
    sA[tid] = e / ssum;
  }
  __syncthreads();
  if (tid < FD) {
    float s = 0.f;
    for (int r = 0; r < K2c; ++r) s += sA[r] * h2b[r * FD + tid];
    Mm[tid] = s;
  }
  __syncthreads();
  if (tid < FD) {
    float s = p.gnb[tid];
    for (int k = 0; k < FD; ++k) s += Mm[k] * p.gnw[k * FD + tid];
    p.out[g * 640 + tid] = s;
  }
}

extern "C" void kernel_launch(void* const* d_in, const int* in_sizes, int n_in,
                              void* d_out, int out_size, void* d_ws, size_t ws_size,
                              hipStream_t stream) {
  (void)n_in; (void)d_ws; (void)ws_size; (void)out_size;
  Params p;
  p.x         = (const float*)d_in[0];
  p.p1_rel_w  = (const float*)d_in[1];
  p.p1_rel_b  = (const float*)d_in[2];
  p.p1_root_w = (const float*)d_in[3];
  p.p1_lin_w  = (const float*)d_in[4];
  p.p1_lin_b  = (const float*)d_in[5];
  p.p1_att_w  = (const float*)d_in[6];
  p.p1_att_b  = (const float*)d_in[7];
  p.p1_le1_w  = (const float*)d_in[8];
  p.p1_le1_b  = (const float*)d_in[9];
  p.p1_le2_w  = (const float*)d_in[10];
  p.p1_le3_w  = (const float*)d_in[11];
  p.p1_le3_b  = (const float*)d_in[12];
  p.p2_rel_w  = (const float*)d_in[13];
  p.p2_rel_b  = (const float*)d_in[14];
  p.p2_root_w = (const float*)d_in[15];
  p.p2_lin_w  = (const float*)d_in[16];
  p.p2_lin_b  = (const float*)d_in[17];
  p.p2_att_w  = (const float*)d_in[18];
  p.p2_att_b  = (const float*)d_in[19];
  p.p2_le1_w  = (const float*)d_in[20];
  p.p2_le1_b  = (const float*)d_in[21];
  p.p2_le2_w  = (const float*)d_in[22];
  p.p2_le3_w  = (const float*)d_in[23];
  p.p2_le3_b  = (const float*)d_in[24];
  p.c1w       = (const float*)d_in[25];
  p.c2w       = (const float*)d_in[26];
  p.ggw       = (const float*)d_in[27];
  p.ggb       = (const float*)d_in[28];
  p.gnw       = (const float*)d_in[29];
  p.gnb       = (const float*)d_in[30];
  p.ei        = (const int*)d_in[31];
  p.out       = (float*)d_out;
  p.etot      = in_sizes[31] / 2;
  mol_kernel<<<dim3(Bc), dim3(NT), 0, stream>>>(p);
}